// Round 17
// baseline (95.413 us; speedup 1.0000x reference)
//
#include <hip/hip_runtime.h>
#include <hip/hip_bf16.h>
#include <hip/hip_fp16.h>
#include <cstdint>
#include <cstddef>

#define NROWS 32768
#define DDIM  64
#define KDIM  8192
#define DELTA 1.25f  // 2*bf16-score-err + 2*fp16 storage err

typedef float  f32x4 __attribute__((ext_vector_type(4)));
typedef short  s16x8 __attribute__((ext_vector_type(8)));
typedef unsigned long long u64;

// Swizzled bf16 layout for MFMA operands: matrix [R][64] stored as 16B chunks,
// chunk_idx(r,d) = (r>>4)*128 + (d>>5)*64 + ((d>>3)&3)*16 + (r&15)
// -> wave frag load (tile,h) = base + lane*16B, fully coalesced.
// wtb holds bf16(-2*w) so MFMA with C-init = wsq produces the score directly.

__device__ __forceinline__ uint32_t fmono(float f) {
    uint32_t u = __float_as_uint(f);
    return (u & 0x80000000u) ? ~u : (u | 0x80000000u);
}

// ================= fast path =================

// prep: w[d][k] -> swizzled bf16 wtb(-2w) + fp32 wt[k][d] + wt4[d4][k] + wsq[k]
__global__ void __launch_bounds__(256)
vq_prep_w(const float* __restrict__ w, ushort* __restrict__ wtb,
          float* __restrict__ wt, float4* __restrict__ wt4,
          float* __restrict__ wsq) {
    __shared__ float tile[64][65];
    const int kbase = blockIdx.x * 64;
    const int t = threadIdx.x, wv = t >> 6, lane = t & 63;
    const int l15 = lane & 15, l4 = (lane >> 4) & 3;
#pragma unroll
    for (int it = 0; it < 16; ++it) {
        int d = it * 4 + wv;
        tile[lane][d] = w[(size_t)d * KDIM + kbase + lane];   // coalesced
    }
    __syncthreads();
    // swizzled bf16 chunks (scaled by -2): wave wv owns 16-row tile
#pragma unroll
    for (int h = 0; h < 2; ++h) {
        s16x8 c;
#pragma unroll
        for (int e = 0; e < 8; ++e) {
            float v = -2.0f * tile[wv * 16 + l15][h * 32 + l4 * 8 + e];
            __hip_bfloat16 hb = __float2bfloat16(v);
            c[e] = *(short*)&hb;
        }
        ((s16x8*)wtb)[(size_t)(blockIdx.x * 4 + wv) * 128 + h * 64 + lane] = c;
    }
    // fp32 wt rows (coalesced 256B per wave-iter)
#pragma unroll
    for (int it = 0; it < 16; ++it) {
        int kk = it * 4 + wv;
        wt[(size_t)(kbase + kk) * DDIM + lane] = tile[kk][lane];
    }
    // wt4[i][k] = float4(wt[k][4i..4i+4]); per (wv,it): 64 consecutive float4 = 1KB
#pragma unroll
    for (int it = 0; it < 4; ++it) {
        int i = wv * 4 + it;
        float4 v;
        v.x = tile[lane][i * 4 + 0];
        v.y = tile[lane][i * 4 + 1];
        v.z = tile[lane][i * 4 + 2];
        v.w = tile[lane][i * 4 + 3];
        wt4[(size_t)i * KDIM + kbase + lane] = v;
    }
    if (wv == 0) {   // lane = k within tile; serial ascending-d fmaf
        float s = 0.f;
#pragma unroll
        for (int d = 0; d < DDIM; ++d) {
            float v = tile[lane][d];
            s = fmaf(v, v, s);
        }
        wsq[kbase + lane] = s;
    }
}

// prep: x -> swizzled bf16 chunks. Wave handles 16 rows; writes coalesced 1KB.
__global__ void __launch_bounds__(256)
vq_prep_x(const float* __restrict__ x, ushort* __restrict__ xb) {
    const int t = threadIdx.x, wv = t >> 6, lane = t & 63;
    const int l15 = lane & 15, l4 = (lane >> 4) & 3;
    const int r = blockIdx.x * 64 + wv * 16 + l15;
#pragma unroll
    for (int h = 0; h < 2; ++h) {
        const float* src = &x[(size_t)r * DDIM + h * 32 + l4 * 8];
        float4 a = *(const float4*)src;
        float4 b = *(const float4*)(src + 4);
        float fv[8] = {a.x, a.y, a.z, a.w, b.x, b.y, b.z, b.w};
        s16x8 c;
#pragma unroll
        for (int e = 0; e < 8; ++e) {
            __hip_bfloat16 hb = __float2bfloat16(fv[e]);
            c[e] = *(short*)&hb;
        }
        ((s16x8*)xb)[(size_t)(blockIdx.x * 4 + wv) * 128 + h * 64 + lane] = c;
    }
}

// pass A: block = 4 waves sharing ONE kg (256 k) staged in LDS; each wave owns
// a different 128 rows (512 rows/block). afrag/wq come from LDS (off the L1
// path); only bfrag + the one-time stage go through L1. Grid = 64 x 32 = 2048.
__global__ void __launch_bounds__(256)
vq_scoreA(const ushort* __restrict__ xb, const ushort* __restrict__ wb,
          const float* __restrict__ wsq, ushort* __restrict__ lsub) {
    __shared__ ushort wlds[2048 * 8];   // 2048 chunks x 16B = 32 KiB (kg's w tiles)
    __shared__ float  wsq_l[256];       // 1 KiB

    const int t = threadIdx.x, wv = t >> 6, lane = t & 63;
    const int l15 = lane & 15, l4 = lane >> 4;
    const int kg    = blockIdx.x & 31;
    const int rbase = (blockIdx.x >> 5) * 512 + wv * 128;  // wave's 128 rows
    const int kbase = kg * 256;

    const s16x8* xs  = (const s16x8*)xb;
    const s16x8* wsx = (const s16x8*)wb;

    // stage the kg's 2048 w-chunks (32 KB) + wsq (1 KB) into LDS
    {
        const size_t cb = (size_t)kg * 2048;
#pragma unroll
        for (int it = 0; it < 8; ++it) {
            int c = it * 256 + t;
            ((s16x8*)wlds)[c] = wsx[cb + c];   // coalesced 4KB per iter
        }
        wsq_l[t] = wsq[kbase + t];
    }

    // bfrag: this wave's 128 rows (global, overlaps staging)
    s16x8 bfrag[8][2];
#pragma unroll
    for (int rt = 0; rt < 8; ++rt)
#pragma unroll
        for (int h = 0; h < 2; ++h)
            bfrag[rt][h] = xs[(size_t)((rbase >> 4) + rt) * 128 + h * 64 + lane];

    __syncthreads();

    const s16x8* wl = (const s16x8*)wlds;
#pragma unroll
    for (int sub = 0; sub < 4; ++sub) {
        s16x8 afrag[4][2];
#pragma unroll
        for (int kt = 0; kt < 4; ++kt)
#pragma unroll
            for (int h = 0; h < 2; ++h)
                afrag[kt][h] = wl[(sub * 4 + kt) * 128 + h * 64 + lane];  // ds_read_b128

        f32x4 wq[4];
#pragma unroll
        for (int kt = 0; kt < 4; ++kt)
            wq[kt] = *(const f32x4*)&wsq_l[sub * 64 + kt * 16 + l4 * 4];

#pragma unroll
        for (int rt = 0; rt < 8; ++rt) {
            f32x4 acc[4];
#pragma unroll
            for (int kt = 0; kt < 4; ++kt) acc[kt] = wq[kt];
#pragma unroll
            for (int kt = 0; kt < 4; ++kt) {
                acc[kt] = __builtin_amdgcn_mfma_f32_16x16x32_bf16(afrag[kt][0], bfrag[rt][0], acc[kt], 0, 0, 0);
                acc[kt] = __builtin_amdgcn_mfma_f32_16x16x32_bf16(afrag[kt][1], bfrag[rt][1], acc[kt], 0, 0, 0);
            }
            float g0 = fminf(fminf(acc[0][0], acc[0][1]), acc[0][2]);
            float g1 = fminf(fminf(acc[0][3], acc[1][0]), acc[1][1]);
            float g2 = fminf(fminf(acc[1][2], acc[1][3]), acc[2][0]);
            float g3 = fminf(fminf(acc[2][1], acc[2][2]), acc[2][3]);
            float g4 = fminf(fminf(acc[3][0], acc[3][1]), acc[3][2]);
            float h0 = fminf(fminf(g0, g1), g2);
            float h1 = fminf(fminf(g3, g4), acc[3][3]);
            float m  = fminf(h0, h1);
            m = fminf(m, __shfl_xor(m, 16));
            m = fminf(m, __shfl_xor(m, 32));
            if (l4 == 0) {
                __half hh = __float2half(m);
                lsub[(size_t)(rbase + rt * 16 + l15) * 128 + kg * 4 + sub] =
                    *(ushort*)&hh;
            }
        }
    }
}

// finish: one wave per row (32768 blocks): threshold -> ballot flags -> exact
// fp32 rescore via wt4 (coalesced), per-lane packed-u64 best, one final
// reduce, fused coalesced gather.
__global__ void __launch_bounds__(64)
vq_finish(const float* __restrict__ x, const float4* __restrict__ wt4,
          const float* __restrict__ wt, const float* __restrict__ wsq,
          const ushort* __restrict__ lsub, float* __restrict__ out) {
    const int lane = threadIdx.x;
    const int row  = blockIdx.x;

    ushort2 us = ((const ushort2*)(lsub + (size_t)row * 128))[lane];
    float v0 = __half2float(*(__half*)&us.x);
    float v1 = __half2float(*(__half*)&us.y);
    float m = fminf(v0, v1);
#pragma unroll
    for (int o = 1; o < 64; o <<= 1) m = fminf(m, __shfl_xor(m, o));
    const float thr = m + DELTA;
    u64 b0 = __ballot(v0 <= thr);   // bit s -> subchunk 2s
    u64 b1 = __ballot(v1 <= thr);   // bit s -> subchunk 2s+1

    // x row: wave-uniform -> scalar loads/SGPRs
    float xs[64];
    const float4* xp = (const float4*)(x + (size_t)row * DDIM);
#pragma unroll
    for (int i = 0; i < 16; ++i) {
        float4 v = xp[i];
        xs[4 * i + 0] = v.x;
        xs[4 * i + 1] = v.y;
        xs[4 * i + 2] = v.z;
        xs[4 * i + 3] = v.w;
    }

    u64 best = ~0ull;
#pragma unroll
    for (int half = 0; half < 2; ++half) {
        u64 b = half ? b1 : b0;
        while (b) {                      // wave-uniform loop
            int s = __ffsll(b) - 1;
            b &= b - 1;
            const int kk = (s * 2 + half) * 64 + lane;   // lane = codeword
            float qq = wsq[kk];
            const float4* wr = wt4 + kk;
            float a0 = 0.f, a1 = 0.f, a2 = 0.f, a3 = 0.f;
#pragma unroll
            for (int i = 0; i < 16; ++i) {   // 16 coalesced 1KB wave loads
                float4 wv4 = wr[(size_t)i * KDIM];
                a0 = fmaf(xs[4 * i + 0], wv4.x, a0);
                a1 = fmaf(xs[4 * i + 1], wv4.y, a1);
                a2 = fmaf(xs[4 * i + 2], wv4.z, a2);
                a3 = fmaf(xs[4 * i + 3], wv4.w, a3);
            }
            float dot = (a0 + a1) + (a2 + a3);   // same pairing/order as before
            float sc  = fmaf(-2.f, dot, qq);
            u64 key = ((u64)fmono(sc) << 32) | (unsigned)kk;
            best = (key < best) ? key : best;    // per-lane, order-independent
        }
    }
#pragma unroll
    for (int sh = 1; sh < 64; sh <<= 1) {        // single final reduce
        u64 o = __shfl_xor(best, sh);
        best = (o < best) ? o : best;
    }
    const int bk = (int)(best & 0xFFFFFFFFull);  // lexicographic => lowest k tie
    out[(size_t)row * DDIM + lane] = wt[(size_t)bk * DDIM + lane];  // coalesced
}

// ================= fallback (round-3 fp32 path, small ws) =================

#define BR 128
#define BK 128
#define DPH 32
typedef float v2f __attribute__((ext_vector_type(2)));

__global__ void fb_prep(const float* __restrict__ w, float* __restrict__ wt,
                        float* __restrict__ wsq) {
    int k = blockIdx.x * blockDim.x + threadIdx.x;
    if (k >= KDIM) return;
    float s = 0.f;
#pragma unroll
    for (int d = 0; d < DDIM; ++d) {
        float v = w[(size_t)d * KDIM + k];
        wt[(size_t)k * DDIM + d] = v;
        s = fmaf(v, v, s);
    }
    wsq[k] = s;
}
__global__ void fb_init(u64* __restrict__ keys) {
    int i = blockIdx.x * blockDim.x + threadIdx.x;
    if (i < NROWS) keys[i] = ~0ull;
}
__global__ void __launch_bounds__(256, 4)
fb_gemm(const float* __restrict__ x, const float* __restrict__ w,
        const float* __restrict__ wsq, u64* __restrict__ keys) {
    __shared__ float xT[DPH][BR];
    __shared__ float wl[DPH][BK];
    const int kblk  = blockIdx.x & (KDIM / BK - 1);
    const int rbase = (blockIdx.x >> 6) * BR;
    const int kbase = kblk * BK;
    const int t     = threadIdx.x;
    const int wave = t >> 6, lane = t & 63;
    const int rg = lane >> 3, cg = lane & 7;
    const int xoff = (wave >> 1) * 64 + rg * 8;
    const int coff = (wave & 1) * 64 + cg * 8;
    v2f acc[8][4];
#pragma unroll
    for (int i = 0; i < 8; ++i)
#pragma unroll
        for (int j = 0; j < 4; ++j) acc[i][j] = (v2f)(0.f);
#pragma unroll
    for (int p = 0; p < 2; ++p) {
        {
            const int row = t & 127, dgrp = t >> 7;
#pragma unroll
            for (int it = 0; it < 4; ++it) {
                const int dl = (dgrp + it * 2) * 4;
                float4 v = *(const float4*)&x[(size_t)(rbase + row) * DDIM + p * DPH + dl];
                xT[dl + 0][row] = v.x; xT[dl + 1][row] = v.y;
                xT[dl + 2][row] = v.z; xT[dl + 3][row] = v.w;
            }
        }
        {
#pragma unroll
            for (int it = 0; it < 4; ++it) {
                const int o4 = t + it * 256;
                const int dl = o4 >> 5, c4 = (o4 & 31) << 2;
                float4 v = *(const float4*)&w[(size_t)(p * DPH + dl) * KDIM + kbase + c4];
                *(float4*)&wl[dl][c4] = v;
            }
        }
        __syncthreads();
#pragma unroll 4
        for (int d = 0; d < DPH; ++d) {
            float4 xa = *(const float4*)&xT[d][xoff];
            float4 xb = *(const float4*)&xT[d][xoff + 4];
            float4 wa = *(const float4*)&wl[d][coff];
            float4 wb = *(const float4*)&wl[d][coff + 4];
            v2f wv0 = {wa.x, wa.y}, wv1 = {wa.z, wa.w};
            v2f wv2 = {wb.x, wb.y}, wv3 = {wb.z, wb.w};
            float xrr[8] = {xa.x, xa.y, xa.z, xa.w, xb.x, xb.y, xb.z, xb.w};
#pragma unroll
            for (int i = 0; i < 8; ++i) {
                v2f xsV = {xrr[i], xrr[i]};
                acc[i][0] = __builtin_elementwise_fma(xsV, wv0, acc[i][0]);
                acc[i][1] = __builtin_elementwise_fma(xsV, wv1, acc[i][1]);
                acc[i][2] = __builtin_elementwise_fma(xsV, wv2, acc[i][2]);
                acc[i][3] = __builtin_elementwise_fma(xsV, wv3, acc[i][3]);
            }
        }
        __syncthreads();
    }
    const int kc = kbase + coff;
    float4 qa = *(const float4*)&wsq[kc];
    float4 qb = *(const float4*)&wsq[kc + 4];
    v2f q2[4] = {{qa.x, qa.y}, {qa.z, qa.w}, {qb.x, qb.y}, {qb.z, qb.w}};
    const v2f neg2 = {-2.f, -2.f};
#pragma unroll
    for (int i = 0; i < 8; ++i) {
        float sc[8];
#pragma unroll
        for (int jj = 0; jj < 4; ++jj) {
            v2f s2 = __builtin_elementwise_fma(neg2, acc[i][jj], q2[jj]);
            sc[2 * jj] = s2.x; sc[2 * jj + 1] = s2.y;
        }
        float bestv = sc[0]; int bj = 0;
#pragma unroll
        for (int j = 1; j < 8; ++j)
            if (sc[j] < bestv) { bestv = sc[j]; bj = j; }
        u64 key = ((u64)fmono(bestv) << 32) | (unsigned)(kc + bj);
        u64 o;
        o = __shfl_xor(key, 1); key = (o < key) ? o : key;
        o = __shfl_xor(key, 2); key = (o < key) ? o : key;
        o = __shfl_xor(key, 4); key = (o < key) ? o : key;
        if (cg == 0) atomicMin(&keys[rbase + xoff + i], key);
    }
}
__global__ void fb_gather(const u64* __restrict__ keys,
                          const float* __restrict__ wt,
                          float* __restrict__ out) {
    int t = blockIdx.x * blockDim.x + threadIdx.x;
    if (t >= NROWS * DDIM) return;
    int row = t >> 6;
    int d   = t & 63;
    int k   = (int)(keys[row] & 0xFFFFFFFFull);
    out[t] = wt[(size_t)k * DDIM + d];
}

// ================= launch =================

extern "C" void kernel_launch(void* const* d_in, const int* in_sizes, int n_in,
                              void* d_out, int out_size, void* d_ws, size_t ws_size,
                              hipStream_t stream) {
    const float* x = (const float*)d_in[0];   // [32768, 64]
    const float* w = (const float*)d_in[1];   // [64, 8192]
    float* out = (float*)d_out;

    char* ws = (char*)d_ws;
    const size_t OFF_WTB  = 0;               // 8192*64*2  = 1 MiB (swizzled bf16 -2w)
    const size_t OFF_WSQ  = 1048576;         // 32 KiB
    const size_t OFF_XB   = 1081344;         // 32768*64*2 = 4 MiB (swizzled bf16)
    const size_t OFF_WT   = 5275648;         // 8192*64*4  = 2 MiB (fp32 rows)
    const size_t OFF_WT4  = 7372800;         // 8192*16*16 = 2 MiB (float4 d-major)
    const size_t OFF_LSUB = 9469952;         // 32768*128*2 = 8 MiB (fp16 sub-mins)
    const size_t NEED     = 17858560;

    if (ws_size >= NEED) {
        ushort* wtb  = (ushort*)(ws + OFF_WTB);
        float*  wsq  = (float*)(ws + OFF_WSQ);
        ushort* xbb  = (ushort*)(ws + OFF_XB);
        float*  wt   = (float*)(ws + OFF_WT);
        float4* wt4  = (float4*)(ws + OFF_WT4);
        ushort* lsub = (ushort*)(ws + OFF_LSUB);

        vq_prep_w<<<KDIM / 64, 256, 0, stream>>>(w, wtb, wt, wt4, wsq);
        vq_prep_x<<<NROWS / 64, 256, 0, stream>>>(x, xbb);
        vq_scoreA<<<(NROWS / 512) * 32, 256, 0, stream>>>(xbb, wtb, wsq, lsub);
        vq_finish<<<NROWS, 64, 0, stream>>>(x, wt4, wt, wsq, lsub, out);
    } else {
        float* wt  = (float*)ws;
        float* wsq = (float*)(ws + 2097152);
        u64*   keys = (u64*)(ws + 2129920);
        fb_prep<<<KDIM / 256, 256, 0, stream>>>(w, wt, wsq);
        fb_init<<<NROWS / 256, 256, 0, stream>>>(keys);
        fb_gemm<<<(NROWS / BR) * (KDIM / BK), 256, 0, stream>>>(x, w, wsq, keys);
        fb_gather<<<(NROWS * DDIM) / 256, 256, 0, stream>>>(keys, wt, out);
    }
}

// Round 18
// 80.408 us; speedup vs baseline: 1.1866x; 1.1866x over previous
//
#include <hip/hip_runtime.h>
#include <hip/hip_bf16.h>
#include <hip/hip_fp16.h>
#include <cstdint>
#include <cstddef>

#define NROWS 32768
#define DDIM  64
#define KDIM  8192
#define DELTA 1.25f  // 2*bf16-score-err + 2*fp16 storage err

typedef float  f32x4 __attribute__((ext_vector_type(4)));
typedef short  s16x8 __attribute__((ext_vector_type(8)));
typedef unsigned long long u64;

// Swizzled bf16 layout for MFMA operands: matrix [R][64] stored as 16B chunks,
// chunk_idx(r,d) = (r>>4)*128 + (d>>5)*64 + ((d>>3)&3)*16 + (r&15)
// -> wave frag load (tile,h) = base + lane*16B, fully coalesced.
// wtb holds bf16(-2*w) so MFMA with C-init = wsq produces the score directly.

__device__ __forceinline__ uint32_t fmono(float f) {
    uint32_t u = __float_as_uint(f);
    return (u & 0x80000000u) ? ~u : (u | 0x80000000u);
}

// ================= fast path =================

// fused prep: blocks [0,128) do w -> wtb(-2w)/wt/wt4/wsq; blocks [128,640) do x -> xb
__global__ void __launch_bounds__(256)
vq_prep(const float* __restrict__ w, const float* __restrict__ x,
        ushort* __restrict__ wtb, float* __restrict__ wt,
        float4* __restrict__ wt4, float* __restrict__ wsq,
        ushort* __restrict__ xb) {
    __shared__ float tile[64][65];
    const int t = threadIdx.x, wv = t >> 6, lane = t & 63;
    const int l15 = lane & 15, l4 = (lane >> 4) & 3;

    if (blockIdx.x < KDIM / 64) {
        const int bid = blockIdx.x;
        const int kbase = bid * 64;
#pragma unroll
        for (int it = 0; it < 16; ++it) {
            int d = it * 4 + wv;
            tile[lane][d] = w[(size_t)d * KDIM + kbase + lane];   // coalesced
        }
        __syncthreads();
        // swizzled bf16 chunks (scaled by -2): wave wv owns 16-row tile
#pragma unroll
        for (int h = 0; h < 2; ++h) {
            s16x8 c;
#pragma unroll
            for (int e = 0; e < 8; ++e) {
                float v = -2.0f * tile[wv * 16 + l15][h * 32 + l4 * 8 + e];
                __hip_bfloat16 hb = __float2bfloat16(v);
                c[e] = *(short*)&hb;
            }
            ((s16x8*)wtb)[(size_t)(bid * 4 + wv) * 128 + h * 64 + lane] = c;
        }
        // fp32 wt rows
#pragma unroll
        for (int it = 0; it < 16; ++it) {
            int kk = it * 4 + wv;
            wt[(size_t)(kbase + kk) * DDIM + lane] = tile[kk][lane];
        }
        // wt4[i][k] = float4(wt[k][4i..4i+4])
#pragma unroll
        for (int it = 0; it < 4; ++it) {
            int i = wv * 4 + it;
            float4 v;
            v.x = tile[lane][i * 4 + 0];
            v.y = tile[lane][i * 4 + 1];
            v.z = tile[lane][i * 4 + 2];
            v.w = tile[lane][i * 4 + 3];
            wt4[(size_t)i * KDIM + kbase + lane] = v;
        }
        if (wv == 0) {   // lane = k within tile; serial ascending-d fmaf
            float s = 0.f;
#pragma unroll
            for (int d = 0; d < DDIM; ++d) {
                float v = tile[lane][d];
                s = fmaf(v, v, s);
            }
            wsq[kbase + lane] = s;
        }
    } else {
        const int bid = blockIdx.x - KDIM / 64;
        const int r = bid * 64 + wv * 16 + l15;
#pragma unroll
        for (int h = 0; h < 2; ++h) {
            const float* src = &x[(size_t)r * DDIM + h * 32 + l4 * 8];
            float4 a = *(const float4*)src;
            float4 b = *(const float4*)(src + 4);
            float fv[8] = {a.x, a.y, a.z, a.w, b.x, b.y, b.z, b.w};
            s16x8 c;
#pragma unroll
            for (int e = 0; e < 8; ++e) {
                __hip_bfloat16 hb = __float2bfloat16(fv[e]);
                c[e] = *(short*)&hb;
            }
            ((s16x8*)xb)[(size_t)(bid * 4 + wv) * 128 + h * 64 + lane] = c;
        }
    }
}

// pass A: wave = 128 rows x 256 k (rt=8), no LDS/barrier (r15 structure).
// bid mapping: rbase = bid&255, kgq = bid>>8 -> the 8 blocks of one row-panel
// share bid%8 (same XCD) -> xb panel L2-resident per XCD.
// lsub store: 4 sub-mins packed per rt -> single 8B store (no 2B scatter).
__global__ void __launch_bounds__(256)
vq_scoreA(const ushort* __restrict__ xb, const ushort* __restrict__ wb,
          const float* __restrict__ wsq, ushort* __restrict__ lsub) {
    const int t = threadIdx.x, wv = t >> 6, lane = t & 63;
    const int l15 = lane & 15, l4 = lane >> 4;
    const int rbase = (blockIdx.x & 255) * 128;
    const int kg    = (blockIdx.x >> 8) * 4 + wv;   // 0..31
    const int kbase = kg * 256;

    const s16x8* xs  = (const s16x8*)xb;
    const s16x8* wsx = (const s16x8*)wb;

    s16x8 bfrag[8][2];
#pragma unroll
    for (int rt = 0; rt < 8; ++rt)
#pragma unroll
        for (int h = 0; h < 2; ++h)
            bfrag[rt][h] = xs[(size_t)((rbase >> 4) + rt) * 128 + h * 64 + lane];

    u64 packs[8];
#pragma unroll
    for (int rt = 0; rt < 8; ++rt) packs[rt] = 0ull;

#pragma unroll
    for (int sub = 0; sub < 4; ++sub) {
        const int kw = kbase + sub * 64;

        s16x8 afrag[4][2];
#pragma unroll
        for (int kt = 0; kt < 4; ++kt)
#pragma unroll
            for (int h = 0; h < 2; ++h)
                afrag[kt][h] = wsx[(size_t)((kw >> 4) + kt) * 128 + h * 64 + lane];

        f32x4 wq[4];
#pragma unroll
        for (int kt = 0; kt < 4; ++kt)
            wq[kt] = *(const f32x4*)&wsq[kw + kt * 16 + l4 * 4];

#pragma unroll
        for (int rt = 0; rt < 8; ++rt) {
            f32x4 acc[4];
#pragma unroll
            for (int kt = 0; kt < 4; ++kt) acc[kt] = wq[kt];
#pragma unroll
            for (int kt = 0; kt < 4; ++kt) {
                acc[kt] = __builtin_amdgcn_mfma_f32_16x16x32_bf16(afrag[kt][0], bfrag[rt][0], acc[kt], 0, 0, 0);
                acc[kt] = __builtin_amdgcn_mfma_f32_16x16x32_bf16(afrag[kt][1], bfrag[rt][1], acc[kt], 0, 0, 0);
            }
            float g0 = fminf(fminf(acc[0][0], acc[0][1]), acc[0][2]);
            float g1 = fminf(fminf(acc[0][3], acc[1][0]), acc[1][1]);
            float g2 = fminf(fminf(acc[1][2], acc[1][3]), acc[2][0]);
            float g3 = fminf(fminf(acc[2][1], acc[2][2]), acc[2][3]);
            float g4 = fminf(fminf(acc[3][0], acc[3][1]), acc[3][2]);
            float h0 = fminf(fminf(g0, g1), g2);
            float h1 = fminf(fminf(g3, g4), acc[3][3]);
            float m  = fminf(h0, h1);
            m = fminf(m, __shfl_xor(m, 16));
            m = fminf(m, __shfl_xor(m, 32));
            __half hh = __float2half(m);
            packs[rt] |= (u64)(*(ushort*)&hh) << (16 * sub);
        }
    }

    if (l4 == 0) {
#pragma unroll
        for (int rt = 0; rt < 8; ++rt)
            *(u64*)&lsub[(size_t)(rbase + rt * 16 + l15) * 128 + kg * 4] = packs[rt];
    }
}

// finish: one wave per row (32768 blocks): threshold -> ballot flags -> exact
// fp32 rescore via wt4 (coalesced), per-lane packed-u64 best, one final
// reduce, fused coalesced gather.
__global__ void __launch_bounds__(64)
vq_finish(const float* __restrict__ x, const float4* __restrict__ wt4,
          const float* __restrict__ wt, const float* __restrict__ wsq,
          const ushort* __restrict__ lsub, float* __restrict__ out) {
    const int lane = threadIdx.x;
    const int row  = blockIdx.x;

    ushort2 us = ((const ushort2*)(lsub + (size_t)row * 128))[lane];
    float v0 = __half2float(*(__half*)&us.x);
    float v1 = __half2float(*(__half*)&us.y);
    float m = fminf(v0, v1);
#pragma unroll
    for (int o = 1; o < 64; o <<= 1) m = fminf(m, __shfl_xor(m, o));
    const float thr = m + DELTA;
    u64 b0 = __ballot(v0 <= thr);   // bit s -> subchunk 2s
    u64 b1 = __ballot(v1 <= thr);   // bit s -> subchunk 2s+1

    // x row: wave-uniform -> scalar loads/SGPRs
    float xs[64];
    const float4* xp = (const float4*)(x + (size_t)row * DDIM);
#pragma unroll
    for (int i = 0; i < 16; ++i) {
        float4 v = xp[i];
        xs[4 * i + 0] = v.x;
        xs[4 * i + 1] = v.y;
        xs[4 * i + 2] = v.z;
        xs[4 * i + 3] = v.w;
    }

    u64 best = ~0ull;
#pragma unroll
    for (int half = 0; half < 2; ++half) {
        u64 b = half ? b1 : b0;
        while (b) {                      // wave-uniform loop
            int s = __ffsll(b) - 1;
            b &= b - 1;
            const int kk = (s * 2 + half) * 64 + lane;   // lane = codeword
            float qq = wsq[kk];
            const float4* wr = wt4 + kk;
            float a0 = 0.f, a1 = 0.f, a2 = 0.f, a3 = 0.f;
#pragma unroll
            for (int i = 0; i < 16; ++i) {   // 16 coalesced 1KB wave loads
                float4 wv4 = wr[(size_t)i * KDIM];
                a0 = fmaf(xs[4 * i + 0], wv4.x, a0);
                a1 = fmaf(xs[4 * i + 1], wv4.y, a1);
                a2 = fmaf(xs[4 * i + 2], wv4.z, a2);
                a3 = fmaf(xs[4 * i + 3], wv4.w, a3);
            }
            float dot = (a0 + a1) + (a2 + a3);   // same pairing/order as before
            float sc  = fmaf(-2.f, dot, qq);
            u64 key = ((u64)fmono(sc) << 32) | (unsigned)kk;
            best = (key < best) ? key : best;    // per-lane, order-independent
        }
    }
#pragma unroll
    for (int sh = 1; sh < 64; sh <<= 1) {        // single final reduce
        u64 o = __shfl_xor(best, sh);
        best = (o < best) ? o : best;
    }
    const int bk = (int)(best & 0xFFFFFFFFull);  // lexicographic => lowest k tie
    out[(size_t)row * DDIM + lane] = wt[(size_t)bk * DDIM + lane];  // coalesced
}

// ================= fallback (round-3 fp32 path, small ws) =================

#define BR 128
#define BK 128
#define DPH 32
typedef float v2f __attribute__((ext_vector_type(2)));

__global__ void fb_prep(const float* __restrict__ w, float* __restrict__ wt,
                        float* __restrict__ wsq) {
    int k = blockIdx.x * blockDim.x + threadIdx.x;
    if (k >= KDIM) return;
    float s = 0.f;
#pragma unroll
    for (int d = 0; d < DDIM; ++d) {
        float v = w[(size_t)d * KDIM + k];
        wt[(size_t)k * DDIM + d] = v;
        s = fmaf(v, v, s);
    }
    wsq[k] = s;
}
__global__ void fb_init(u64* __restrict__ keys) {
    int i = blockIdx.x * blockDim.x + threadIdx.x;
    if (i < NROWS) keys[i] = ~0ull;
}
__global__ void __launch_bounds__(256, 4)
fb_gemm(const float* __restrict__ x, const float* __restrict__ w,
        const float* __restrict__ wsq, u64* __restrict__ keys) {
    __shared__ float xT[DPH][BR];
    __shared__ float wl[DPH][BK];
    const int kblk  = blockIdx.x & (KDIM / BK - 1);
    const int rbase = (blockIdx.x >> 6) * BR;
    const int kbase = kblk * BK;
    const int t     = threadIdx.x;
    const int wave = t >> 6, lane = t & 63;
    const int rg = lane >> 3, cg = lane & 7;
    const int xoff = (wave >> 1) * 64 + rg * 8;
    const int coff = (wave & 1) * 64 + cg * 8;
    v2f acc[8][4];
#pragma unroll
    for (int i = 0; i < 8; ++i)
#pragma unroll
        for (int j = 0; j < 4; ++j) acc[i][j] = (v2f)(0.f);
#pragma unroll
    for (int p = 0; p < 2; ++p) {
        {
            const int row = t & 127, dgrp = t >> 7;
#pragma unroll
            for (int it = 0; it < 4; ++it) {
                const int dl = (dgrp + it * 2) * 4;
                float4 v = *(const float4*)&x[(size_t)(rbase + row) * DDIM + p * DPH + dl];
                xT[dl + 0][row] = v.x; xT[dl + 1][row] = v.y;
                xT[dl + 2][row] = v.z; xT[dl + 3][row] = v.w;
            }
        }
        {
#pragma unroll
            for (int it = 0; it < 4; ++it) {
                const int o4 = t + it * 256;
                const int dl = o4 >> 5, c4 = (o4 & 31) << 2;
                float4 v = *(const float4*)&w[(size_t)(p * DPH + dl) * KDIM + kbase + c4];
                *(float4*)&wl[dl][c4] = v;
            }
        }
        __syncthreads();
#pragma unroll 4
        for (int d = 0; d < DPH; ++d) {
            float4 xa = *(const float4*)&xT[d][xoff];
            float4 xb = *(const float4*)&xT[d][xoff + 4];
            float4 wa = *(const float4*)&wl[d][coff];
            float4 wb = *(const float4*)&wl[d][coff + 4];
            v2f wv0 = {wa.x, wa.y}, wv1 = {wa.z, wa.w};
            v2f wv2 = {wb.x, wb.y}, wv3 = {wb.z, wb.w};
            float xrr[8] = {xa.x, xa.y, xa.z, xa.w, xb.x, xb.y, xb.z, xb.w};
#pragma unroll
            for (int i = 0; i < 8; ++i) {
                v2f xsV = {xrr[i], xrr[i]};
                acc[i][0] = __builtin_elementwise_fma(xsV, wv0, acc[i][0]);
                acc[i][1] = __builtin_elementwise_fma(xsV, wv1, acc[i][1]);
                acc[i][2] = __builtin_elementwise_fma(xsV, wv2, acc[i][2]);
                acc[i][3] = __builtin_elementwise_fma(xsV, wv3, acc[i][3]);
            }
        }
        __syncthreads();
    }
    const int kc = kbase + coff;
    float4 qa = *(const float4*)&wsq[kc];
    float4 qb = *(const float4*)&wsq[kc + 4];
    v2f q2[4] = {{qa.x, qa.y}, {qa.z, qa.w}, {qb.x, qb.y}, {qb.z, qb.w}};
    const v2f neg2 = {-2.f, -2.f};
#pragma unroll
    for (int i = 0; i < 8; ++i) {
        float sc[8];
#pragma unroll
        for (int jj = 0; jj < 4; ++jj) {
            v2f s2 = __builtin_elementwise_fma(neg2, acc[i][jj], q2[jj]);
            sc[2 * jj] = s2.x; sc[2 * jj + 1] = s2.y;
        }
        float bestv = sc[0]; int bj = 0;
#pragma unroll
        for (int j = 1; j < 8; ++j)
            if (sc[j] < bestv) { bestv = sc[j]; bj = j; }
        u64 key = ((u64)fmono(bestv) << 32) | (unsigned)(kc + bj);
        u64 o;
        o = __shfl_xor(key, 1); key = (o < key) ? o : key;
        o = __shfl_xor(key, 2); key = (o < key) ? o : key;
        o = __shfl_xor(key, 4); key = (o < key) ? o : key;
        if (cg == 0) atomicMin(&keys[rbase + xoff + i], key);
    }
}
__global__ void fb_gather(const u64* __restrict__ keys,
                          const float* __restrict__ wt,
                          float* __restrict__ out) {
    int t = blockIdx.x * blockDim.x + threadIdx.x;
    if (t >= NROWS * DDIM) return;
    int row = t >> 6;
    int d   = t & 63;
    int k   = (int)(keys[row] & 0xFFFFFFFFull);
    out[t] = wt[(size_t)k * DDIM + d];
}

// ================= launch =================

extern "C" void kernel_launch(void* const* d_in, const int* in_sizes, int n_in,
                              void* d_out, int out_size, void* d_ws, size_t ws_size,
                              hipStream_t stream) {
    const float* x = (const float*)d_in[0];   // [32768, 64]
    const float* w = (const float*)d_in[1];   // [64, 8192]
    float* out = (float*)d_out;

    char* ws = (char*)d_ws;
    const size_t OFF_WTB  = 0;               // 8192*64*2  = 1 MiB (swizzled bf16 -2w)
    const size_t OFF_WSQ  = 1048576;         // 32 KiB
    const size_t OFF_XB   = 1081344;         // 32768*64*2 = 4 MiB (swizzled bf16)
    const size_t OFF_WT   = 5275648;         // 8192*64*4  = 2 MiB (fp32 rows)
    const size_t OFF_WT4  = 7372800;         // 8192*16*16 = 2 MiB (float4 d-major)
    const size_t OFF_LSUB = 9469952;         // 32768*128*2 = 8 MiB (fp16 sub-mins)
    const size_t NEED     = 17858560;

    if (ws_size >= NEED) {
        ushort* wtb  = (ushort*)(ws + OFF_WTB);
        float*  wsq  = (float*)(ws + OFF_WSQ);
        ushort* xbb  = (ushort*)(ws + OFF_XB);
        float*  wt   = (float*)(ws + OFF_WT);
        float4* wt4  = (float4*)(ws + OFF_WT4);
        ushort* lsub = (ushort*)(ws + OFF_LSUB);

        vq_prep<<<KDIM / 64 + NROWS / 64, 256, 0, stream>>>(w, x, wtb, wt, wt4, wsq, xbb);
        vq_scoreA<<<(NROWS / 128) * 8, 256, 0, stream>>>(xbb, wtb, wsq, lsub);
        vq_finish<<<NROWS, 64, 0, stream>>>(x, wt4, wt, wsq, lsub, out);
    } else {
        float* wt  = (float*)ws;
        float* wsq = (float*)(ws + 2097152);
        u64*   keys = (u64*)(ws + 2129920);
        fb_prep<<<KDIM / 256, 256, 0, stream>>>(w, wt, wsq);
        fb_init<<<NROWS / 256, 256, 0, stream>>>(keys);
        fb_gemm<<<(NROWS / BR) * (KDIM / BK), 256, 0, stream>>>(x, w, wsq, keys);
        fb_gather<<<(NROWS * DDIM) / 256, 256, 0, stream>>>(keys, wt, out);
    }
}